// Round 1
// 130.000 us; speedup vs baseline: 1.0304x; 1.0304x over previous
//
#include <hip/hip_runtime.h>

#define BD 8
#define SD 64
#define CD 3
#define HD 224
#define WD 224
#define ED 128
#define PD 16
#define HWD (HD*WD)
#define KD (CD*PD*PD)   /* 768 */
#define PRT 8           /* partitions per (b,c) for the hierarchical scatter */
#define CHK (HWD/PRT)   /* 6272 pixels per partition */

typedef float v2f __attribute__((ext_vector_type(2)));

// All buffers fp32 (confirmed R6+ passes). Scratch in module globals; every
// byte is fully overwritten each call (no zero-init dispatch) and there are
// NO global atomics anywhere (R9: atomic scatter = 30MB line-grain RMW ~66us;
// R10: flat gather 64x label re-scan = 133us; R11: hierarchical = win, 135.6us).
// R12 negative: PIX=4 weight amortization neutral. R13 negative: k_out 4-i
// blocks (128 total) -> occupancy collapse, 50us; grid >= 256 blocks beats
// any L2-traffic saving at this size.
__device__ float              g_part[BD * CD * PRT * SD * 256];  // 12.6 MB partials
__device__ int                g_labels[BD * HWD];
__device__ unsigned long long g_ppres[BD * PRT];                 // presence per (b,part)

// Kernel 1: 3x3 SAME conv -> argmax(64ch) -> labels.
// R14 change: weights+bias staged in LDS [64][28] (112B row stride, 8B-aligned)
// and read as broadcast ds_read_b64 pairs; taps accumulated as float2 packed
// FMA (v_pk_fma_f32 on gfx950) with bias folded into the last pair via
// (pix26, 1.0f) . (w26, bias). Kills the per-s-iteration serial scalar-load +
// 27-deep dependent FMA chain that capped the old version; VALU issue count
// per s-iter drops ~60 -> ~18 ops.
__global__ __launch_bounds__(256) void k_labels(
    const float* __restrict__ img,
    const float* __restrict__ wsp,
    const float* __restrict__ bsp)
{
    __shared__ __align__(16) float w_s[SD * 28];   // 7 KB: [s][0..26]=w, [s][27]=bias
    const int tid = threadIdx.x;
    for (int t = tid; t < SD * 28; t += 256) {
        const int s = t / 28, j = t - s * 28;
        w_s[t] = (j < 27) ? wsp[s * 27 + j] : bsp[s];
    }
    __syncthreads();

    const int p = blockIdx.x * 256 + tid;
    const int b = blockIdx.y;
    const int h = p / WD;
    const int w = p - h * WD;

    const float* ib = img + (size_t)b * CD * HWD;
    float pix[27];
    #pragma unroll
    for (int c = 0; c < 3; ++c)
        #pragma unroll
        for (int dh = 0; dh < 3; ++dh)
            #pragma unroll
            for (int dw = 0; dw < 3; ++dw) {
                int hh = h + dh - 1, ww = w + dw - 1;
                bool ok = (hh >= 0) & (hh < HD) & (ww >= 0) & (ww < WD);
                pix[(c * 3 + dh) * 3 + dw] = ok ? ib[c * HWD + hh * WD + ww] : 0.f;
            }

    v2f p2[13];
    #pragma unroll
    for (int t = 0; t < 13; ++t) { p2[t].x = pix[2 * t]; p2[t].y = pix[2 * t + 1]; }
    const v2f plast = { pix[26], 1.0f };

    float best = -INFINITY;
    int bi = 0;
    for (int s = 0; s < SD; ++s) {
        const v2f* wrow = (const v2f*)(w_s + s * 28);  // same addr all lanes -> LDS broadcast
        v2f acc = { 0.f, 0.f };
        #pragma unroll
        for (int t = 0; t < 13; ++t)
            acc = __builtin_elementwise_fma(p2[t], wrow[t], acc);
        acc = __builtin_elementwise_fma(plast, wrow[13], acc);   // + w26*pix26, + bias
        const float a = acc.x + acc.y;
        if (a > best) { best = a; bi = s; }   // strict > = first max (jnp.argmax)
    }
    g_labels[b * HWD + p] = bi;
}

// Kernel 2: hierarchical scatter. Block = (partition, channel, batch); owns a
// 6272-pixel chunk, accumulates into a 64KB LDS table [lab][cell] via LDS
// atomics (<=4-way conflicts), writes its partial table exclusively (coalesced).
// Presence mask per (b,part) from in-register OR + wave shfl-OR (c==0 blocks).
__global__ __launch_bounds__(256) void k_hist(const float* __restrict__ img)
{
    const int part = blockIdx.x, c = blockIdx.y, b = blockIdx.z;
    const int tid = threadIdx.x;

    __shared__ float acc[SD * 256];            // 64 KB
    __shared__ unsigned long long pm;
    #pragma unroll
    for (int k = 0; k < 16; ++k)
        ((float4*)acc)[k * 256 + tid] = make_float4(0.f, 0.f, 0.f, 0.f);
    if (tid == 0) pm = 0ull;
    __syncthreads();

    const int start = part * CHK;
    const int*   lb = g_labels + (size_t)b * HWD;
    const float* ic = img + ((size_t)b * CD + c) * HWD;

    unsigned long long m = 0ull;
    for (int p = start + tid; p < start + CHK; p += 256) {
        const int lab = lb[p];                 // coalesced, L2-resident
        const int h = p / WD, w = p - h * WD;
        const int cell = ((h & 15) << 4) | (w & 15);
        atomicAdd(&acc[lab * 256 + cell], ic[p]);
        m |= 1ull << lab;
    }
    #pragma unroll
    for (int d = 1; d < 64; d <<= 1) m |= __shfl_xor(m, d, 64);
    if ((tid & 63) == 0) atomicOr(&pm, m);
    __syncthreads();

    float4* dst = (float4*)(g_part + (((size_t)(b * CD + c)) * PRT + part) * (SD * 256));
    #pragma unroll
    for (int k = 0; k < 16; ++k)
        dst[k * 256 + tid] = ((float4*)acc)[k * 256 + tid];
    if (c == 0 && tid == 0) g_ppres[b * PRT + part] = pm;
}

// Kernel 3: out[b,i,e] = bias[e] + (1/196)*dot(G[b,uniq(b,i),:], wp[e,:]).
// R11-proven exact form: 512 blocks (one per (i,b)), merge of PRT partials
// folded in (192 threads build the 3KB g-row in LDS), lane=k-dim coalesced
// wp dot + shfl reduce.
__global__ __launch_bounds__(256) void k_out(
    const float* __restrict__ wp,
    const float* __restrict__ bp,
    float* __restrict__ out)
{
    __shared__ float4 gs4[KD / 4];             // 192 float4 = 3 KB
    const int i = blockIdx.x;
    const int b = blockIdx.y;
    const int tid = threadIdx.x;
    const int lane = tid & 63;
    const int wv = tid >> 6;

    unsigned long long m = 0ull;
    #pragma unroll
    for (int p2 = 0; p2 < PRT; ++p2) m |= g_ppres[b * PRT + p2];  // uniform -> s_load

    int l = 0;
    if (i < __popcll(m)) {
        unsigned long long mm = m;
        for (int t = 0; t < i; ++t) mm &= mm - 1;   // clear i lowest set bits
        l = __builtin_ctzll(mm);                    // i-th smallest label (sorted unique)
    }

    if (tid < KD / 4) {
        const int c = tid >> 6, cell4 = tid & 63;
        const float4* src = (const float4*)g_part
            + ((size_t)(b * CD + c) * PRT) * 4096 + l * 64 + cell4;
        float4 s = src[0];
        #pragma unroll
        for (int p2 = 1; p2 < PRT; ++p2) {
            float4 v = src[(size_t)p2 * 4096];
            s.x += v.x; s.y += v.y; s.z += v.z; s.w += v.w;
        }
        gs4[tid] = s;
    }
    __syncthreads();

    const float4 g0 = gs4[lane], g1 = gs4[lane + 64], g2 = gs4[lane + 128];

    #pragma unroll 4
    for (int j = 0; j < 32; ++j) {
        const int e = wv * 32 + j;
        const float4* wr = (const float4*)(wp + (size_t)e * KD);
        float4 a0 = wr[lane], a1 = wr[lane + 64], a2 = wr[lane + 128];  // coalesced 1KB/wave
        float acc = g0.x * a0.x;
        acc = fmaf(g0.y, a0.y, acc); acc = fmaf(g0.z, a0.z, acc); acc = fmaf(g0.w, a0.w, acc);
        acc = fmaf(g1.x, a1.x, acc); acc = fmaf(g1.y, a1.y, acc);
        acc = fmaf(g1.z, a1.z, acc); acc = fmaf(g1.w, a1.w, acc);
        acc = fmaf(g2.x, a2.x, acc); acc = fmaf(g2.y, a2.y, acc);
        acc = fmaf(g2.z, a2.z, acc); acc = fmaf(g2.w, a2.w, acc);
        #pragma unroll
        for (int off = 32; off; off >>= 1) acc += __shfl_xor(acc, off, 64);
        if (lane == 0)
            out[(size_t)(b * SD + i) * ED + e] = bp[e] + acc * (1.f / 196.f);
    }
}

extern "C" void kernel_launch(void* const* d_in, const int* in_sizes, int n_in,
                              void* d_out, int out_size, void* d_ws, size_t ws_size,
                              hipStream_t stream) {
    const float *img = nullptr, *wsp = nullptr, *bsp = nullptr, *wp = nullptr, *bp = nullptr;
    for (int i = 0; i < n_in; ++i) {
        switch (in_sizes[i]) {
            case BD * CD * HWD:      img = (const float*)d_in[i]; break;  // 1204224
            case SD * CD * 9:        wsp = (const float*)d_in[i]; break;  // 1728
            case SD:                 bsp = (const float*)d_in[i]; break;  // 64
            case ED * CD * PD * PD:  wp  = (const float*)d_in[i]; break;  // 98304
            case ED:                 bp  = (const float*)d_in[i]; break;  // 128
        }
    }
    float* out = (float*)d_out;

    dim3 g1(HWD / 256, BD, 1);
    k_labels<<<g1, 256, 0, stream>>>(img, wsp, bsp);

    dim3 g2(PRT, CD, BD);
    k_hist<<<g2, 256, 0, stream>>>(img);

    dim3 g3(SD, BD, 1);
    k_out<<<g3, 256, 0, stream>>>(wp, bp, out);
}

// Round 2
// 121.403 us; speedup vs baseline: 1.1034x; 1.0708x over previous
//
#include <hip/hip_runtime.h>

#define BD 8
#define SD 64
#define CD 3
#define HD 224
#define WD 224
#define ED 128
#define PD 16
#define HWD (HD*WD)
#define KD (CD*PD*PD)   /* 768 */
#define PRT 8           /* partitions per (b,c) for the hierarchical scatter */
#define CHK (HWD/PRT)   /* 6272 pixels per partition */

typedef float v2f __attribute__((ext_vector_type(2)));

// All buffers fp32. Scratch in module globals; every byte fully overwritten
// each call, no global atomics (R9/R10/R11 history). Timed region model (R15):
// ~3x 256MiB harness poison fills (~121.5us, untouchable) + our kernels
// (~8.5us). R14 win: k_labels LDS-broadcast pk-FMA, -4us. This round: k_labels
// pair-packed channels (kills per-s h-add + bias FMA), k_out e-split for 2x
// occupancy, k_hist explicit prefetch.
__device__ float              g_part[BD * CD * PRT * SD * 256];  // 12.6 MB partials
__device__ int                g_labels[BD * HWD];
__device__ unsigned long long g_ppres[BD * PRT];                 // presence per (b,part)

// Kernel 1: 3x3 SAME conv -> argmax(64ch) -> labels.
// Weights staged in LDS interleaved by channel PAIR: row q holds
// (w[2q][j], w[2q+1][j]) for j<27 plus (b[2q], b[2q+1]) at slot 27
// (224B row, 16B-aligned). Inner loop: acc(v2f) = bias-pair; 27 pk-FMA with
// pixel-duplicated v2f regs; 2 ordered strict-> compares -> first-max argmax.
__global__ __launch_bounds__(256) void k_labels(
    const float* __restrict__ img,
    const float* __restrict__ wsp,
    const float* __restrict__ bsp)
{
    __shared__ __align__(16) float w_s[(SD / 2) * 56];   // 7 KB
    const int tid = threadIdx.x;
    #pragma unroll
    for (int t = tid; t < (SD / 2) * 56; t += 256) {
        const int q = t / 56, r = t - q * 56;
        const int j = r >> 1, s = 2 * q + (r & 1);
        w_s[t] = (j < 27) ? wsp[s * 27 + j] : bsp[s];
    }
    __syncthreads();

    const int p = blockIdx.x * 256 + tid;
    const int b = blockIdx.y;
    const int h = p / WD;
    const int w = p - h * WD;

    const float* ib = img + (size_t)b * CD * HWD;
    float pix[27];
    #pragma unroll
    for (int c = 0; c < 3; ++c)
        #pragma unroll
        for (int dh = 0; dh < 3; ++dh)
            #pragma unroll
            for (int dw = 0; dw < 3; ++dw) {
                int hh = h + dh - 1, ww = w + dw - 1;
                bool ok = (hh >= 0) & (hh < HD) & (ww >= 0) & (ww < WD);
                pix[(c * 3 + dh) * 3 + dw] = ok ? ib[c * HWD + hh * WD + ww] : 0.f;
            }

    v2f pd[27];
    #pragma unroll
    for (int j = 0; j < 27; ++j) { pd[j].x = pix[j]; pd[j].y = pix[j]; }

    float best = -INFINITY;
    int bi = 0;
    for (int q = 0; q < SD / 2; ++q) {
        const v2f* wrow = (const v2f*)w_s + q * 28;  // same addr all lanes -> broadcast
        v2f acc = wrow[27];                          // (bias[2q], bias[2q+1])
        #pragma unroll
        for (int j = 0; j < 27; ++j)
            acc = __builtin_elementwise_fma(pd[j], wrow[j], acc);
        if (acc.x > best) { best = acc.x; bi = 2 * q; }       // strict > = first max
        if (acc.y > best) { best = acc.y; bi = 2 * q + 1; }
    }
    g_labels[b * HWD + p] = bi;
}

// Kernel 2: hierarchical scatter. Block = (partition, channel, batch); owns a
// 6272-pixel chunk, accumulates into a 64KB LDS table [lab][cell] via LDS
// atomics (<=4-way conflicts), writes its partial table exclusively (coalesced).
// Explicit next-iteration prefetch decouples global-load latency from the
// atomic chain. Presence mask per (b,part) from shfl-OR (c==0 blocks).
__global__ __launch_bounds__(256) void k_hist(const float* __restrict__ img)
{
    const int part = blockIdx.x, c = blockIdx.y, b = blockIdx.z;
    const int tid = threadIdx.x;

    __shared__ float acc[SD * 256];            // 64 KB
    __shared__ unsigned long long pm;
    #pragma unroll
    for (int k = 0; k < 16; ++k)
        ((float4*)acc)[k * 256 + tid] = make_float4(0.f, 0.f, 0.f, 0.f);
    if (tid == 0) pm = 0ull;
    __syncthreads();

    const int start = part * CHK;
    const int end   = start + CHK;
    const int*   lb = g_labels + (size_t)b * HWD;
    const float* ic = img + ((size_t)b * CD + c) * HWD;

    unsigned long long m = 0ull;
    int p = start + tid;
    int   lab = (p < end) ? lb[p] : 0;
    float val = (p < end) ? ic[p] : 0.f;
    while (p < end) {
        const int pn = p + 256;
        const int   labn = (pn < end) ? lb[pn] : 0;      // prefetch next
        const float valn = (pn < end) ? ic[pn] : 0.f;
        const int h = p / WD, w = p - h * WD;
        const int cell = ((h & 15) << 4) | (w & 15);
        atomicAdd(&acc[lab * 256 + cell], val);
        m |= 1ull << lab;
        p = pn; lab = labn; val = valn;
    }
    #pragma unroll
    for (int d = 1; d < 64; d <<= 1) m |= __shfl_xor(m, d, 64);
    if ((tid & 63) == 0) atomicOr(&pm, m);
    __syncthreads();

    float4* dst = (float4*)(g_part + (((size_t)(b * CD + c)) * PRT + part) * (SD * 256));
    #pragma unroll
    for (int k = 0; k < 16; ++k)
        dst[k * 256 + tid] = ((float4*)acc)[k * 256 + tid];
    if (c == 0 && tid == 0) g_ppres[b * PRT + part] = pm;
}

// Kernel 3: out[b,i,e] = bias[e] + (1/196)*dot(G[b,uniq(b,i),:], wp[e,:]).
// R16 change: e-split z=2 -> 1024 blocks (4 blocks/CU, 4 waves/SIMD) halves
// the per-wave exposed L2-load + shfl-chain latency; each block now does 64 e
// (wave: 16 iters). gs4 merge duplicated per z (cheap, L2-hot).
__global__ __launch_bounds__(256) void k_out(
    const float* __restrict__ wp,
    const float* __restrict__ bp,
    float* __restrict__ out)
{
    __shared__ float4 gs4[KD / 4];             // 192 float4 = 3 KB
    const int i = blockIdx.x;
    const int b = blockIdx.y;
    const int z = blockIdx.z;
    const int tid = threadIdx.x;
    const int lane = tid & 63;
    const int wv = tid >> 6;

    unsigned long long m = 0ull;
    #pragma unroll
    for (int p2 = 0; p2 < PRT; ++p2) m |= g_ppres[b * PRT + p2];  // uniform -> s_load

    int l = 0;
    if (i < __popcll(m)) {
        unsigned long long mm = m;
        for (int t = 0; t < i; ++t) mm &= mm - 1;   // clear i lowest set bits
        l = __builtin_ctzll(mm);                    // i-th smallest label (sorted unique)
    }

    if (tid < KD / 4) {
        const int c = tid >> 6, cell4 = tid & 63;
        const float4* src = (const float4*)g_part
            + ((size_t)(b * CD + c) * PRT) * 4096 + l * 64 + cell4;
        float4 s = src[0];
        #pragma unroll
        for (int p2 = 1; p2 < PRT; ++p2) {
            float4 v = src[(size_t)p2 * 4096];
            s.x += v.x; s.y += v.y; s.z += v.z; s.w += v.w;
        }
        gs4[tid] = s;
    }
    __syncthreads();

    const float4 g0 = gs4[lane], g1 = gs4[lane + 64], g2 = gs4[lane + 128];

    #pragma unroll 4
    for (int j = 0; j < 16; ++j) {
        const int e = z * 64 + wv * 16 + j;
        const float4* wr = (const float4*)(wp + (size_t)e * KD);
        float4 a0 = wr[lane], a1 = wr[lane + 64], a2 = wr[lane + 128];  // coalesced 1KB/wave
        float acc = g0.x * a0.x;
        acc = fmaf(g0.y, a0.y, acc); acc = fmaf(g0.z, a0.z, acc); acc = fmaf(g0.w, a0.w, acc);
        acc = fmaf(g1.x, a1.x, acc); acc = fmaf(g1.y, a1.y, acc);
        acc = fmaf(g1.z, a1.z, acc); acc = fmaf(g1.w, a1.w, acc);
        acc = fmaf(g2.x, a2.x, acc); acc = fmaf(g2.y, a2.y, acc);
        acc = fmaf(g2.z, a2.z, acc); acc = fmaf(g2.w, a2.w, acc);
        #pragma unroll
        for (int off = 32; off; off >>= 1) acc += __shfl_xor(acc, off, 64);
        if (lane == 0)
            out[(size_t)(b * SD + i) * ED + e] = bp[e] + acc * (1.f / 196.f);
    }
}

extern "C" void kernel_launch(void* const* d_in, const int* in_sizes, int n_in,
                              void* d_out, int out_size, void* d_ws, size_t ws_size,
                              hipStream_t stream) {
    const float *img = nullptr, *wsp = nullptr, *bsp = nullptr, *wp = nullptr, *bp = nullptr;
    for (int i = 0; i < n_in; ++i) {
        switch (in_sizes[i]) {
            case BD * CD * HWD:      img = (const float*)d_in[i]; break;  // 1204224
            case SD * CD * 9:        wsp = (const float*)d_in[i]; break;  // 1728
            case SD:                 bsp = (const float*)d_in[i]; break;  // 64
            case ED * CD * PD * PD:  wp  = (const float*)d_in[i]; break;  // 98304
            case ED:                 bp  = (const float*)d_in[i]; break;  // 128
        }
    }
    float* out = (float*)d_out;

    dim3 g1(HWD / 256, BD, 1);
    k_labels<<<g1, 256, 0, stream>>>(img, wsp, bsp);

    dim3 g2(PRT, CD, BD);
    k_hist<<<g2, 256, 0, stream>>>(img);

    dim3 g3(SD, BD, 2);
    k_out<<<g3, 256, 0, stream>>>(wp, bp, out);
}

// Round 3
// 119.224 us; speedup vs baseline: 1.1236x; 1.0183x over previous
//
#include <hip/hip_runtime.h>

#define BD 8
#define SD 64
#define CD 3
#define HD 224
#define WD 224
#define ED 128
#define PD 16
#define HWD (HD*WD)
#define KD (CD*PD*PD)   /* 768 */
#define PRT 8           /* partitions per (b,c) for the hierarchical scatter */
#define CHK (HWD/PRT)   /* 6272 pixels per partition */
#define IG 4            /* i's (segments) amortized per k_out block */

typedef float v2f __attribute__((ext_vector_type(2)));

// All buffers fp32. Scratch in module globals; every byte fully overwritten
// each call, no global atomics (R9/R10/R11 history). Timed-region model (R17):
// 2x 256MiB harness poison fills (~82us, untouchable) + our kernels (~39us).
// R14 win: k_labels LDS-broadcast pk-FMA (-4). R16 win: pair-pack + k_out
// e-split + k_hist prefetch (-8.6). This round: k_out IG=4 wp-read
// amortization (L2 traffic 220MB->100MB, blocks stay at 512) + k_hist int4/
// float4 vector loads (4px/group, rows divisible by 4 so groups never split).
__device__ float              g_part[BD * CD * PRT * SD * 256];  // 12.6 MB partials
__device__ int                g_labels[BD * HWD];
__device__ unsigned long long g_ppres[BD * PRT];                 // presence per (b,part)

// Kernel 1: 3x3 SAME conv -> argmax(64ch) -> labels. At fp32-VALU floor
// (~5us): weights in LDS interleaved by channel PAIR (row q = (w[2q],w[2q+1])
// taps + bias pair), broadcast ds_read_b64, 27 pk-FMA per pair, ordered
// strict-> compares = jnp first-max argmax.
__global__ __launch_bounds__(256) void k_labels(
    const float* __restrict__ img,
    const float* __restrict__ wsp,
    const float* __restrict__ bsp)
{
    __shared__ __align__(16) float w_s[(SD / 2) * 56];   // 7 KB
    const int tid = threadIdx.x;
    #pragma unroll
    for (int t = tid; t < (SD / 2) * 56; t += 256) {
        const int q = t / 56, r = t - q * 56;
        const int j = r >> 1, s = 2 * q + (r & 1);
        w_s[t] = (j < 27) ? wsp[s * 27 + j] : bsp[s];
    }
    __syncthreads();

    const int p = blockIdx.x * 256 + tid;
    const int b = blockIdx.y;
    const int h = p / WD;
    const int w = p - h * WD;

    const float* ib = img + (size_t)b * CD * HWD;
    float pix[27];
    #pragma unroll
    for (int c = 0; c < 3; ++c)
        #pragma unroll
        for (int dh = 0; dh < 3; ++dh)
            #pragma unroll
            for (int dw = 0; dw < 3; ++dw) {
                int hh = h + dh - 1, ww = w + dw - 1;
                bool ok = (hh >= 0) & (hh < HD) & (ww >= 0) & (ww < WD);
                pix[(c * 3 + dh) * 3 + dw] = ok ? ib[c * HWD + hh * WD + ww] : 0.f;
            }

    v2f pd[27];
    #pragma unroll
    for (int j = 0; j < 27; ++j) { pd[j].x = pix[j]; pd[j].y = pix[j]; }

    float best = -INFINITY;
    int bi = 0;
    for (int q = 0; q < SD / 2; ++q) {
        const v2f* wrow = (const v2f*)w_s + q * 28;  // same addr all lanes -> broadcast
        v2f acc = wrow[27];                          // (bias[2q], bias[2q+1])
        #pragma unroll
        for (int j = 0; j < 27; ++j)
            acc = __builtin_elementwise_fma(pd[j], wrow[j], acc);
        if (acc.x > best) { best = acc.x; bi = 2 * q; }       // strict > = first max
        if (acc.y > best) { best = acc.y; bi = 2 * q + 1; }
    }
    g_labels[b * HWD + p] = bi;
}

// Kernel 2: hierarchical scatter. Block = (partition, channel, batch); owns a
// 6272-pixel chunk, accumulates into a 64KB LDS table [lab][cell] via LDS
// atomics (<=4-way conflicts), writes its partial table exclusively
// (coalesced). R17: int4/float4 loads, 4 aligned pixels per group (224%4==0,
// CHK%4==0 -> groups never cross rows; w0&15 in {0,4,8,12} so base+3<=255).
// 6 unconditional unrolled iterations + 32-thread tail; loads pipeline across
// the fire-and-forget LDS atomics.
__global__ __launch_bounds__(256) void k_hist(const float* __restrict__ img)
{
    const int part = blockIdx.x, c = blockIdx.y, b = blockIdx.z;
    const int tid = threadIdx.x;

    __shared__ float acc[SD * 256];            // 64 KB
    __shared__ unsigned long long pm;
    #pragma unroll
    for (int k = 0; k < 16; ++k)
        ((float4*)acc)[k * 256 + tid] = make_float4(0.f, 0.f, 0.f, 0.f);
    if (tid == 0) pm = 0ull;
    __syncthreads();

    const int start = part * CHK;
    const int*   lb = g_labels + (size_t)b * HWD;
    const float* ic = img + ((size_t)b * CD + c) * HWD;

    unsigned long long m = 0ull;

    #define HIST_GROUP(g)                                                  \
    {                                                                      \
        const int p4 = start + (g) * 4;                                    \
        const int4   l4 = *(const int4*)(lb + p4);                         \
        const float4 v4 = *(const float4*)(ic + p4);                       \
        const int h = p4 / WD;                                             \
        const int w0 = p4 - h * WD;                                        \
        const int base = ((h & 15) << 4) | (w0 & 15);                      \
        atomicAdd(&acc[l4.x * 256 + base + 0], v4.x);                      \
        atomicAdd(&acc[l4.y * 256 + base + 1], v4.y);                      \
        atomicAdd(&acc[l4.z * 256 + base + 2], v4.z);                      \
        atomicAdd(&acc[l4.w * 256 + base + 3], v4.w);                      \
        m |= 1ull << l4.x; m |= 1ull << l4.y;                              \
        m |= 1ull << l4.z; m |= 1ull << l4.w;                              \
    }

    #pragma unroll
    for (int it = 0; it < 6; ++it) HIST_GROUP(tid + it * 256);  // 6*256 = 1536 groups
    if (tid < (CHK / 4 - 6 * 256)) HIST_GROUP(tid + 6 * 256);   // tail: 32 groups
    #undef HIST_GROUP

    #pragma unroll
    for (int d = 1; d < 64; d <<= 1) m |= __shfl_xor(m, d, 64);
    if ((tid & 63) == 0) atomicOr(&pm, m);
    __syncthreads();

    float4* dst = (float4*)(g_part + (((size_t)(b * CD + c)) * PRT + part) * (SD * 256));
    #pragma unroll
    for (int k = 0; k < 16; ++k)
        dst[k * 256 + tid] = ((float4*)acc)[k * 256 + tid];
    if (c == 0 && tid == 0) g_ppres[b * PRT + part] = pm;
}

// Kernel 3: out[b,i,e] = bias[e] + (1/196)*dot(G[b,uniq(b,i),:], wp[e,:]).
// R17: IG=4 segments per block, 4-way e-split -> grid (16,8,4) = 512 blocks
// (R13's collapse was at 128 blocks; 512 is the R11-proven count). Each wp
// e-row load now feeds 4 dots: wp L2 traffic 197MB -> 49MB; merge 4x3KB rows
// built by all 256 threads (3 float4 slots each).
__global__ __launch_bounds__(256) void k_out(
    const float* __restrict__ wp,
    const float* __restrict__ bp,
    float* __restrict__ out)
{
    __shared__ float4 gs4[IG][KD / 4];         // 4 x 192 float4 = 12 KB
    const int ig = blockIdx.x;                 // i group: i = ig*4 .. ig*4+3
    const int b = blockIdx.y;
    const int z = blockIdx.z;                  // e base = z*32
    const int tid = threadIdx.x;
    const int lane = tid & 63;
    const int wv = tid >> 6;

    unsigned long long m = 0ull;
    #pragma unroll
    for (int p2 = 0; p2 < PRT; ++p2) m |= g_ppres[b * PRT + p2];  // uniform -> s_load
    const int nu = __popcll(m);

    int ls[IG];
    #pragma unroll
    for (int ii = 0; ii < IG; ++ii) {
        const int i = ig * IG + ii;
        int l = 0;
        if (i < nu) {
            unsigned long long mm = m;
            for (int t = 0; t < i; ++t) mm &= mm - 1;   // clear i lowest set bits
            l = __builtin_ctzll(mm);                    // i-th smallest label
        }
        ls[ii] = l;                                     // pad -> 0, matches jnp pad
    }

    // merge PRT partials for 4 labels: 768 float4 slots, 3 per thread
    #pragma unroll
    for (int k = 0; k < 3; ++k) {
        const int t = tid + k * 256;
        const int ii = t / (KD / 4 / 1) / 1;            // t/192
        const int ii_ = t / 192, idx = t - ii_ * 192;
        (void)ii;
        const int c = idx >> 6, cell4 = idx & 63;
        const float4* src = (const float4*)g_part
            + ((size_t)(b * CD + c) * PRT) * 4096 + ls[ii_] * 64 + cell4;
        float4 s = src[0];
        #pragma unroll
        for (int p2 = 1; p2 < PRT; ++p2) {
            float4 v = src[(size_t)p2 * 4096];
            s.x += v.x; s.y += v.y; s.z += v.z; s.w += v.w;
        }
        gs4[ii_][idx] = s;
    }
    __syncthreads();

    float4 G[IG][3];
    #pragma unroll
    for (int ii = 0; ii < IG; ++ii) {
        G[ii][0] = gs4[ii][lane];
        G[ii][1] = gs4[ii][lane + 64];
        G[ii][2] = gs4[ii][lane + 128];
    }

    #pragma unroll 2
    for (int j = 0; j < 8; ++j) {
        const int e = z * 32 + wv * 8 + j;
        const float4* wr = (const float4*)(wp + (size_t)e * KD);
        const float4 a0 = wr[lane], a1 = wr[lane + 64], a2 = wr[lane + 128];
        float acc[IG];
        #pragma unroll
        for (int ii = 0; ii < IG; ++ii) {
            float t = G[ii][0].x * a0.x;
            t = fmaf(G[ii][0].y, a0.y, t); t = fmaf(G[ii][0].z, a0.z, t);
            t = fmaf(G[ii][0].w, a0.w, t);
            t = fmaf(G[ii][1].x, a1.x, t); t = fmaf(G[ii][1].y, a1.y, t);
            t = fmaf(G[ii][1].z, a1.z, t); t = fmaf(G[ii][1].w, a1.w, t);
            t = fmaf(G[ii][2].x, a2.x, t); t = fmaf(G[ii][2].y, a2.y, t);
            t = fmaf(G[ii][2].z, a2.z, t); t = fmaf(G[ii][2].w, a2.w, t);
            acc[ii] = t;
        }
        #pragma unroll
        for (int off = 32; off; off >>= 1) {
            #pragma unroll
            for (int ii = 0; ii < IG; ++ii) acc[ii] += __shfl_xor(acc[ii], off, 64);
        }
        if (lane == 0) {
            #pragma unroll
            for (int ii = 0; ii < IG; ++ii)
                out[(size_t)(b * SD + ig * IG + ii) * ED + e] = bp[e] + acc[ii] * (1.f / 196.f);
        }
    }
}

extern "C" void kernel_launch(void* const* d_in, const int* in_sizes, int n_in,
                              void* d_out, int out_size, void* d_ws, size_t ws_size,
                              hipStream_t stream) {
    const float *img = nullptr, *wsp = nullptr, *bsp = nullptr, *wp = nullptr, *bp = nullptr;
    for (int i = 0; i < n_in; ++i) {
        switch (in_sizes[i]) {
            case BD * CD * HWD:      img = (const float*)d_in[i]; break;  // 1204224
            case SD * CD * 9:        wsp = (const float*)d_in[i]; break;  // 1728
            case SD:                 bsp = (const float*)d_in[i]; break;  // 64
            case ED * CD * PD * PD:  wp  = (const float*)d_in[i]; break;  // 98304
            case ED:                 bp  = (const float*)d_in[i]; break;  // 128
        }
    }
    float* out = (float*)d_out;

    dim3 g1(HWD / 256, BD, 1);
    k_labels<<<g1, 256, 0, stream>>>(img, wsp, bsp);

    dim3 g2(PRT, CD, BD);
    k_hist<<<g2, 256, 0, stream>>>(img);

    dim3 g3(SD / IG, BD, 4);
    k_out<<<g3, 256, 0, stream>>>(wp, bp, out);
}